// Round 1
// baseline (189.686 us; speedup 1.0000x reference)
//
#include <hip/hip_runtime.h>
#include <hip/hip_bf16.h>

#define NPTS 8192
#define GRID_CELLS 9216
#define HEIGHT_F 96.0f

// Workspace layout (bytes):
//   0       : unsigned nn2[8192]    (float bits, atomicMin; values >= 0)
//   32768   : int      rank[8192]   (pz sort rank, atomicAdd)
//   65536   : float    px_s[8192]   (sorted by pz)
//   98304   : float    py_s[8192]
//   131072  : float    pz_s[8192]
//   163840  : double   sum_nn
//   163848  : float    delta2
// total 163852 bytes

__global__ __launch_bounds__(256) void k_init(unsigned* __restrict__ nn2,
                                              int* __restrict__ rank,
                                              double* __restrict__ sum,
                                              float* __restrict__ delta2) {
    int i = blockIdx.x * 256 + threadIdx.x;
    if (i < NPTS) { nn2[i] = 0x7F800000u; rank[i] = 0; }
    if (i == 0) { *sum = 0.0; *delta2 = 0.0f; }
}

// grid (32 i-blocks, 32 j-chunks), block 256.
// Fused: NN min-distance partial (atomicMin on float bits) + pz rank partial.
__global__ __launch_bounds__(256) void k_nn_rank(const float* __restrict__ pts,
                                                 unsigned* __restrict__ nn2,
                                                 int* __restrict__ rank) {
    __shared__ float4 s[256];  // (px, py, pz, sq)
    const int tid = threadIdx.x;
    const int i = blockIdx.x * 256 + tid;
    const int j0 = blockIdx.y * 256;
    {
        int j = j0 + tid;
        float x = pts[3 * j + 0] * HEIGHT_F;
        float y = pts[3 * j + 1] * HEIGHT_F;
        float z = pts[3 * j + 2] * HEIGHT_F;
        s[tid] = make_float4(x, y, z, x * x + y * y + z * z);
    }
    float xi = pts[3 * i + 0] * HEIGHT_F;
    float yi = pts[3 * i + 1] * HEIGHT_F;
    float zi = pts[3 * i + 2] * HEIGHT_F;
    float sqi = xi * xi + yi * yi + zi * zi;
    __syncthreads();

    float mn = 3.0e38f;
    int rk = 0;
    #pragma unroll 8
    for (int k = 0; k < 256; k++) {
        float4 p = s[k];
        int jg = j0 + k;
        // same formula as reference: sq_i + sq_j - 2*dot  (min_j max(.,0) == max(min_j .,0))
        float d2 = sqi + p.w - 2.0f * (xi * p.x + yi * p.y + zi * p.z);
        d2 = fmaxf(d2, 0.0f);
        if (jg != i) mn = fminf(mn, d2);
        // stable pz rank (index tiebreak -> bijection)
        if ((p.z < zi) || (p.z == zi && jg < i)) rk++;
    }
    atomicMin(&nn2[i], __float_as_uint(mn));   // non-neg float bits order == uint order
    atomicAdd(&rank[i], rk);
}

__global__ __launch_bounds__(256) void k_sum(const unsigned* __restrict__ nn2,
                                             double* __restrict__ sum) {
    int i = blockIdx.x * 256 + threadIdx.x;
    float v = sqrtf(__uint_as_float(nn2[i]));
    #pragma unroll
    for (int off = 32; off > 0; off >>= 1) v += __shfl_down(v, off, 64);
    __shared__ float sw[4];
    int lane = threadIdx.x & 63, w = threadIdx.x >> 6;
    if (lane == 0) sw[w] = v;
    __syncthreads();
    if (threadIdx.x == 0) {
        float b = sw[0] + sw[1] + sw[2] + sw[3];
        atomicAdd(sum, (double)b);
    }
}

__global__ void k_delta(const double* __restrict__ sum, float* __restrict__ delta2) {
    float mean = (float)(*sum / (double)NPTS);
    float avg = 3.0f * mean;       // M_FACTOR * mean
    *delta2 = 3.0f * avg;          // M_FACTOR * avg
}

__global__ __launch_bounds__(256) void k_scatter(const float* __restrict__ pts,
                                                 const int* __restrict__ rank,
                                                 float* __restrict__ pxs,
                                                 float* __restrict__ pys,
                                                 float* __restrict__ pzs) {
    int i = blockIdx.x * 256 + threadIdx.x;
    int r = rank[i];
    pxs[r] = pts[3 * i + 0] * HEIGHT_F;
    pys[r] = pts[3 * i + 1] * HEIGHT_F;
    pzs[r] = pts[3 * i + 2] * HEIGHT_F;
}

// one block per grid cell; thread t owns sorted indices [32t, 32t+32)
__global__ __launch_bounds__(256) void k_median(const float* __restrict__ pxs,
                                                const float* __restrict__ pys,
                                                const float* __restrict__ pzs,
                                                const float* __restrict__ delta2p,
                                                float* __restrict__ out) {
    const int g = blockIdx.x;
    const int t = threadIdx.x;
    const int row = g / 96, col = g % 96;
    const float d = *delta2p;
    const float Xf = (float)(col - 48);
    const float Yf = (float)(row - 48);
    // NOTE: replicates reference exactly: px upper bound uses Yr, not Xr.
    const float xlo = Xf - d, xhi = Yf + d, ylo = Yf - d, yhi = Yf + d;

    const int base = t * 32;
    const float4* px4 = (const float4*)(pxs + base);
    const float4* py4 = (const float4*)(pys + base);

    unsigned maskbits = 0;
    int cnt = 0;
    #pragma unroll
    for (int k8 = 0; k8 < 8; k8++) {
        float4 a = px4[k8];
        float4 b = py4[k8];
        float ax[4] = {a.x, a.y, a.z, a.w};
        float by[4] = {b.x, b.y, b.z, b.w};
        #pragma unroll
        for (int q = 0; q < 4; q++) {
            bool m = (ax[q] >= xlo) & (ax[q] <= xhi) & (by[q] >= ylo) & (by[q] <= yhi);
            maskbits |= ((unsigned)m) << (k8 * 4 + q);
            cnt += (int)m;
        }
    }

    __shared__ int s_cnt[256];
    __shared__ float s_val[2];
    s_cnt[t] = cnt;
    __syncthreads();
    int incl = cnt;
    #pragma unroll
    for (int off = 1; off < 256; off <<= 1) {
        int v = (t >= off) ? s_cnt[t - off] : 0;
        __syncthreads();
        incl += v;
        s_cnt[t] = incl;
        __syncthreads();
    }
    const int c = s_cnt[255];
    if (c == 0) {
        if (t == 0) out[g] = 0.0f;
        return;
    }
    const int lo = (c - 1) >> 1;   // c>=1 so trunc==floor; clip never binds
    const int hi = c >> 1;
    const int e = incl - cnt;      // exclusive prefix

    #pragma unroll
    for (int sel = 0; sel < 2; sel++) {
        int rk = sel ? hi : lo;
        if (rk >= e && rk < e + cnt) {
            int need = rk - e;               // need < cnt
            unsigned mb = maskbits;
            for (int q = 0; q < need; q++) mb &= (mb - 1);  // drop 'need' lowest set bits
            int k = __ffs(mb) - 1;
            s_val[sel] = pzs[base + k];
        }
    }
    __syncthreads();
    if (t == 0) {
        float med = 0.5f * (s_val[0] + s_val[1]);
        out[g] = (med + 48.0f) * (1.0f / 96.0f);
    }
}

extern "C" void kernel_launch(void* const* d_in, const int* in_sizes, int n_in,
                              void* d_out, int out_size, void* d_ws, size_t ws_size,
                              hipStream_t stream) {
    const float* pts = (const float*)d_in[0];
    float* out = (float*)d_out;

    char* ws = (char*)d_ws;
    unsigned* nn2 = (unsigned*)(ws + 0);
    int* rank     = (int*)(ws + 32768);
    float* pxs    = (float*)(ws + 65536);
    float* pys    = (float*)(ws + 98304);
    float* pzs    = (float*)(ws + 131072);
    double* sum   = (double*)(ws + 163840);
    float* delta2 = (float*)(ws + 163848);

    k_init<<<NPTS / 256, 256, 0, stream>>>(nn2, rank, sum, delta2);
    k_nn_rank<<<dim3(NPTS / 256, NPTS / 256), 256, 0, stream>>>(pts, nn2, rank);
    k_sum<<<NPTS / 256, 256, 0, stream>>>(nn2, sum);
    k_delta<<<1, 1, 0, stream>>>(sum, delta2);
    k_scatter<<<NPTS / 256, 256, 0, stream>>>(pts, rank, pxs, pys, pzs);
    k_median<<<GRID_CELLS, 256, 0, stream>>>(pxs, pys, pzs, delta2, out);
}

// Round 2
// 178.105 us; speedup vs baseline: 1.0650x; 1.0650x over previous
//
#include <hip/hip_runtime.h>
#include <hip/hip_bf16.h>

#define NPTS 8192
#define HF 96.0f

// Workspace layout (bytes):
//   0       : unsigned nn2[8192]     (float bits, atomicMin; values >= 0)
//   32768   : int      rank[8192]    (pz sort rank, atomicAdd)
//   65536   : float2   pxy[8192]     (px,py sorted by pz)
//   131072  : float    pz_s[8192]
//   163840  : float    delta2
// total 163844 bytes

__global__ __launch_bounds__(256) void k_init(unsigned* __restrict__ nn2,
                                              int* __restrict__ rank) {
    int i = blockIdx.x * 256 + threadIdx.x;
    nn2[i] = 0x7F800000u;  // +inf bits
    rank[i] = 0;
}

// grid (32 i-blocks, 8 j-slices of 1024), block 256. Loops 4 LDS subtiles.
// Fused: NN min-distance partial (atomicMin on float bits) + pz rank partial.
__global__ __launch_bounds__(256) void k_nn_rank(const float* __restrict__ pts,
                                                 unsigned* __restrict__ nn2,
                                                 int* __restrict__ rank) {
    __shared__ float4 s[256];  // (px, py, pz, sq)
    const int tid = threadIdx.x;
    const int i = blockIdx.x * 256 + tid;

    const float xi = pts[3 * i + 0] * HF;
    const float yi = pts[3 * i + 1] * HF;
    const float zi = pts[3 * i + 2] * HF;
    const float sqi = xi * xi + yi * yi + zi * zi;

    float mn = 3.0e38f;
    int rk = 0;
    for (int st = 0; st < 4; ++st) {
        const int j0 = blockIdx.y * 1024 + st * 256;
        {
            int j = j0 + tid;
            float x = pts[3 * j + 0] * HF;
            float y = pts[3 * j + 1] * HF;
            float z = pts[3 * j + 2] * HF;
            s[tid] = make_float4(x, y, z, x * x + y * y + z * z);
        }
        __syncthreads();
        #pragma unroll 8
        for (int k = 0; k < 256; k++) {
            float4 p = s[k];
            int jg = j0 + k;
            // same formula as reference: sq_i + sq_j - 2*dot
            float d2 = sqi + p.w - 2.0f * (xi * p.x + yi * p.y + zi * p.z);
            d2 = fmaxf(d2, 0.0f);           // min_j max(.,0) == max(min_j .,0)
            if (jg != i) mn = fminf(mn, d2);
            // stable pz rank (index tiebreak -> bijection)
            if ((p.z < zi) || (p.z == zi && jg < i)) rk++;
        }
        __syncthreads();
    }
    atomicMin(&nn2[i], __float_as_uint(mn));  // non-neg float bits order == uint order
    atomicAdd(&rank[i], rk);
}

// single block: mean(sqrt(nn2)) -> delta2 = 3*(3*mean)
__global__ __launch_bounds__(256) void k_sumdelta(const unsigned* __restrict__ nn2,
                                                  float* __restrict__ delta2) {
    const int t = threadIdx.x;
    const int lane = t & 63, w = t >> 6;
    double acc = 0.0;
    #pragma unroll 8
    for (int m = 0; m < 32; ++m)
        acc += (double)sqrtf(__uint_as_float(nn2[t + 256 * m]));
    #pragma unroll
    for (int off = 32; off > 0; off >>= 1) acc += __shfl_down(acc, off, 64);
    __shared__ double sw[4];
    if (lane == 0) sw[w] = acc;
    __syncthreads();
    if (t == 0) {
        double s = sw[0] + sw[1] + sw[2] + sw[3];
        float mean = (float)(s / (double)NPTS);
        float avg = 3.0f * mean;   // M_FACTOR * mean
        *delta2 = 3.0f * avg;      // M_FACTOR * avg
    }
}

__global__ __launch_bounds__(256) void k_scatter(const float* __restrict__ pts,
                                                 const int* __restrict__ rank,
                                                 float2* __restrict__ pxy,
                                                 float* __restrict__ pzs) {
    int i = blockIdx.x * 256 + threadIdx.x;
    int r = rank[i];
    pxy[r] = make_float2(pts[3 * i + 0] * HF, pts[3 * i + 1] * HF);
    pzs[r] = pts[3 * i + 2] * HF;
}

// One block per (row, group of 8 cols). Thread t owns point 256k+t of chunk k
// (pz-sorted order) -> coalesced float2 loads. Membership recorded as per-wave
// 64-bit ballots in LDS; rank selection done per-wave in the epilogue.
// NOTE: replicates reference exactly: px upper bound uses Yr (row-uniform), not Xr.
__global__ __launch_bounds__(256) void k_median(const float2* __restrict__ pxy,
                                                const float* __restrict__ pzs,
                                                const float* __restrict__ d2p,
                                                float* __restrict__ out) {
    __shared__ unsigned long long bal[8][4][32];  // [cell][wave][chunk]
    const int t = threadIdx.x;
    const int lane = t & 63;
    const int w = t >> 6;
    const int row = blockIdx.y;      // 96
    const int cg = blockIdx.x;       // 12 col-groups of 8
    const float d = *d2p;
    const float Yf = (float)(row - 48);
    const float ylo = Yf - d, yhi = Yf + d, xhi = Yf + d;
    float xlo[8];
    #pragma unroll
    for (int c = 0; c < 8; ++c) xlo[c] = (float)(cg * 8 + c - 48) - d;

    #pragma unroll 4
    for (int k = 0; k < 32; ++k) {
        float2 p = pxy[(k << 8) + t];
        bool pre = (p.y >= ylo) && (p.y <= yhi) && (p.x <= xhi);
        unsigned long long b[8];
        #pragma unroll
        for (int c = 0; c < 8; ++c) b[c] = __ballot(pre && (p.x >= xlo[c]));
        if (lane == 0) {
            #pragma unroll
            for (int c = 0; c < 8; ++c) bal[c][w][k] = b[c];
        }
    }
    __syncthreads();

    // wave w handles cells 2w and 2w+1; lanes 0..31 each own one chunk
    #pragma unroll
    for (int c2 = 0; c2 < 2; ++c2) {
        const int c = w * 2 + c2;
        const int l = (lane < 32) ? lane : 31;
        const unsigned long long bw0 = bal[c][0][l];
        const unsigned long long bw1 = bal[c][1][l];
        const unsigned long long bw2 = bal[c][2][l];
        const unsigned long long bw3 = bal[c][3][l];
        const int cnt = __popcll(bw0) + __popcll(bw1) + __popcll(bw2) + __popcll(bw3);
        const int cl = (lane < 32) ? cnt : 0;
        int incl = cl;
        #pragma unroll
        for (int off = 1; off < 64; off <<= 1) {
            int v = __shfl_up(incl, off, 64);
            if (lane >= off) incl += v;
        }
        const int ct = __shfl(incl, 63, 64);  // total count c
        const int og = row * 96 + cg * 8 + c;
        if (ct == 0) {
            if (lane == 0) out[og] = 0.0f;
            continue;
        }
        const int excl = incl - cl;
        float vv[2];
        #pragma unroll
        for (int sel = 0; sel < 2; ++sel) {
            const int target = sel ? (ct >> 1) : ((ct - 1) >> 1);
            const bool pred = (lane < 32) && (target >= excl) && (target < excl + cl);
            unsigned long long bm = __ballot(pred);
            int src = __ffsll(bm) - 1;  // exactly one lane holds the target
            float val = 0.0f;
            if (pred) {
                int r = target - excl;
                int pc0 = __popcll(bw0), pc1 = __popcll(bw1), pc2 = __popcll(bw2);
                unsigned long long x;
                int base;
                if (r < pc0)              { x = bw0; base = 0; }
                else if (r < pc0 + pc1)   { x = bw1; base = 64;  r -= pc0; }
                else if (r < pc0+pc1+pc2) { x = bw2; base = 128; r -= pc0 + pc1; }
                else                      { x = bw3; base = 192; r -= pc0 + pc1 + pc2; }
                for (int q = 0; q < r; ++q) x &= x - 1;  // drop r lowest set bits
                val = pzs[(lane << 8) + base + (__ffsll(x) - 1)];
            }
            vv[sel] = __shfl(val, src, 64);
        }
        if (lane == 0) {
            float med = 0.5f * (vv[0] + vv[1]);
            out[og] = (med + 48.0f) * (1.0f / 96.0f);
        }
    }
}

extern "C" void kernel_launch(void* const* d_in, const int* in_sizes, int n_in,
                              void* d_out, int out_size, void* d_ws, size_t ws_size,
                              hipStream_t stream) {
    const float* pts = (const float*)d_in[0];
    float* out = (float*)d_out;

    char* ws = (char*)d_ws;
    unsigned* nn2 = (unsigned*)(ws + 0);
    int* rank     = (int*)(ws + 32768);
    float2* pxy   = (float2*)(ws + 65536);
    float* pzs    = (float*)(ws + 131072);
    float* delta2 = (float*)(ws + 163840);

    k_init<<<NPTS / 256, 256, 0, stream>>>(nn2, rank);
    k_nn_rank<<<dim3(32, 8), 256, 0, stream>>>(pts, nn2, rank);
    k_sumdelta<<<1, 256, 0, stream>>>(nn2, delta2);
    k_scatter<<<NPTS / 256, 256, 0, stream>>>(pts, rank, pxy, pzs);
    k_median<<<dim3(12, 96), 256, 0, stream>>>(pxy, pzs, delta2, out);
}

// Round 3
// 113.580 us; speedup vs baseline: 1.6701x; 1.5681x over previous
//
#include <hip/hip_runtime.h>
#include <hip/hip_bf16.h>

#define NPTS 8192
#define HF 96.0f

// Workspace layout (bytes):
//   0       : unsigned nn2[8192]     (float bits, atomicMin; values >= 0)
//   32768   : int      rank[8192]    (pz sort rank, atomicAdd)
//   65536   : float2   pxy[8192]     (px,py sorted by pz)
//   131072  : float    pz_s[8192]
//   163840  : float    delta2

__global__ __launch_bounds__(256) void k_init(unsigned* __restrict__ nn2,
                                              int* __restrict__ rank) {
    int i = blockIdx.x * 256 + threadIdx.x;
    nn2[i] = 0x7F800000u;  // +inf bits (identity for min of non-neg floats)
    rank[i] = 0;
}

// monotone (z, idx) -> u64 key; strict total order, one v_cmp_lt_u64 per pair
__device__ __forceinline__ unsigned long long zkey(float z, int idx) {
    unsigned u = __float_as_uint(z);
    unsigned m = (unsigned)((int)u >> 31) | 0x80000000u;  // neg: FFFFFFFF, pos: 80000000
    return ((unsigned long long)(u ^ m) << 13) | (unsigned)idx;
}

// grid (32 i-blocks, 32 j-slices), block 256, 4 blocks/CU.
// Fused: NN min-distance partial (atomicMin on float bits) + pz rank partial.
__global__ __launch_bounds__(256) void k_nn_rank(const float* __restrict__ pts,
                                                 unsigned* __restrict__ nn2,
                                                 int* __restrict__ rank) {
    __shared__ float4 s4[256];               // (px, py, pz, sq)
    __shared__ unsigned long long sk[256];   // z-order key
    const int tid = threadIdx.x;
    const int i = blockIdx.x * 256 + tid;
    const int j0 = blockIdx.y * 256;
    {
        int j = j0 + tid;
        float x = pts[3 * j + 0] * HF;
        float y = pts[3 * j + 1] * HF;
        float z = pts[3 * j + 2] * HF;
        s4[tid] = make_float4(x, y, z, x * x + y * y + z * z);
        sk[tid] = zkey(z, j);
    }
    const float xi = pts[3 * i + 0] * HF;
    const float yi = pts[3 * i + 1] * HF;
    const float zi = pts[3 * i + 2] * HF;
    const float sqi = xi * xi + yi * yi + zi * zi;
    const unsigned long long ki = zkey(zi, i);
    __syncthreads();

    float mn = 3.0e38f;
    int rk = 0;
    if (blockIdx.x != blockIdx.y) {          // off-diagonal: no self-pair possible
        #pragma unroll 8
        for (int k = 0; k < 256; ++k) {
            float4 p = s4[k];
            float d2 = sqi + p.w - 2.0f * (xi * p.x + yi * p.y + zi * p.z);
            mn = fminf(mn, d2);
            rk += (int)(sk[k] < ki);
        }
    } else {                                 // diagonal: skip k == tid
        #pragma unroll 8
        for (int k = 0; k < 256; ++k) {
            float4 p = s4[k];
            float d2 = sqi + p.w - 2.0f * (xi * p.x + yi * p.y + zi * p.z);
            if (k != tid) mn = fminf(mn, d2);
            rk += (int)(sk[k] < ki);
        }
    }
    // clamp commutes with min across slices: min_s max(m_s,0) == max(min_s m_s,0)
    mn = fmaxf(mn, 0.0f);
    atomicMin(&nn2[i], __float_as_uint(mn));  // non-neg float bits order == uint order
    atomicAdd(&rank[i], rk);
}

// Fused scatter + delta2: all blocks scatter their 256 points; block 0 also
// reduces mean(sqrt(nn2)) -> delta2 = 3*(3*mean). Both depend only on k_nn_rank.
__global__ __launch_bounds__(256) void k_mid(const float* __restrict__ pts,
                                             const int* __restrict__ rank,
                                             const unsigned* __restrict__ nn2,
                                             float2* __restrict__ pxy,
                                             float* __restrict__ pzs,
                                             float* __restrict__ delta2) {
    const int t = threadIdx.x;
    const int i = blockIdx.x * 256 + t;
    const int r = rank[i];
    pxy[r] = make_float2(pts[3 * i + 0] * HF, pts[3 * i + 1] * HF);
    pzs[r] = pts[3 * i + 2] * HF;
    if (blockIdx.x == 0) {
        double acc = 0.0;
        #pragma unroll 8
        for (int m = 0; m < 32; ++m)
            acc += (double)sqrtf(__uint_as_float(nn2[t + 256 * m]));
        #pragma unroll
        for (int off = 32; off > 0; off >>= 1) acc += __shfl_down(acc, off, 64);
        __shared__ double sw[4];
        if ((t & 63) == 0) sw[t >> 6] = acc;
        __syncthreads();
        if (t == 0) {
            double s = sw[0] + sw[1] + sw[2] + sw[3];
            float mean = (float)(s / (double)NPTS);
            float avg = 3.0f * mean;   // M_FACTOR * mean
            *delta2 = 3.0f * avg;      // M_FACTOR * avg
        }
    }
}

// One block per (row, group of 8 cols). Thread t owns point 256k+t of chunk k
// (pz-sorted order) -> coalesced float2 loads. Membership recorded as per-wave
// 64-bit ballots in LDS; rank selection done per-wave in the epilogue.
// NOTE: replicates reference exactly: px upper bound uses Yr (row-uniform), not Xr.
__global__ __launch_bounds__(256) void k_median(const float2* __restrict__ pxy,
                                                const float* __restrict__ pzs,
                                                const float* __restrict__ d2p,
                                                float* __restrict__ out) {
    __shared__ unsigned long long bal[8][4][32];  // [cell][wave][chunk]
    const int t = threadIdx.x;
    const int lane = t & 63;
    const int w = t >> 6;
    const int row = blockIdx.y;      // 96
    const int cg = blockIdx.x;       // 12 col-groups of 8
    const float d = *d2p;
    const float Yf = (float)(row - 48);
    const float ylo = Yf - d, yhi = Yf + d, xhi = Yf + d;
    float xlo[8];
    #pragma unroll
    for (int c = 0; c < 8; ++c) xlo[c] = (float)(cg * 8 + c - 48) - d;

    #pragma unroll 4
    for (int k = 0; k < 32; ++k) {
        float2 p = pxy[(k << 8) + t];
        bool pre = (p.y >= ylo) && (p.y <= yhi) && (p.x <= xhi);
        unsigned long long b[8];
        #pragma unroll
        for (int c = 0; c < 8; ++c) b[c] = __ballot(pre && (p.x >= xlo[c]));
        if (lane == 0) {
            #pragma unroll
            for (int c = 0; c < 8; ++c) bal[c][w][k] = b[c];
        }
    }
    __syncthreads();

    // wave w handles cells 2w and 2w+1; lanes 0..31 each own one chunk
    #pragma unroll
    for (int c2 = 0; c2 < 2; ++c2) {
        const int c = w * 2 + c2;
        const int l = (lane < 32) ? lane : 31;
        const unsigned long long bw0 = bal[c][0][l];
        const unsigned long long bw1 = bal[c][1][l];
        const unsigned long long bw2 = bal[c][2][l];
        const unsigned long long bw3 = bal[c][3][l];
        const int cnt = __popcll(bw0) + __popcll(bw1) + __popcll(bw2) + __popcll(bw3);
        const int cl = (lane < 32) ? cnt : 0;
        int incl = cl;
        #pragma unroll
        for (int off = 1; off < 64; off <<= 1) {
            int v = __shfl_up(incl, off, 64);
            if (lane >= off) incl += v;
        }
        const int ct = __shfl(incl, 63, 64);  // total count c
        const int og = row * 96 + cg * 8 + c;
        if (ct == 0) {
            if (lane == 0) out[og] = 0.0f;
            continue;
        }
        const int excl = incl - cl;
        float vv[2];
        #pragma unroll
        for (int sel = 0; sel < 2; ++sel) {
            const int target = sel ? (ct >> 1) : ((ct - 1) >> 1);
            const bool pred = (lane < 32) && (target >= excl) && (target < excl + cl);
            unsigned long long bm = __ballot(pred);
            int src = __ffsll(bm) - 1;  // exactly one lane holds the target
            float val = 0.0f;
            if (pred) {
                int r = target - excl;
                int pc0 = __popcll(bw0), pc1 = __popcll(bw1), pc2 = __popcll(bw2);
                unsigned long long x;
                int base;
                if (r < pc0)              { x = bw0; base = 0; }
                else if (r < pc0 + pc1)   { x = bw1; base = 64;  r -= pc0; }
                else if (r < pc0+pc1+pc2) { x = bw2; base = 128; r -= pc0 + pc1; }
                else                      { x = bw3; base = 192; r -= pc0 + pc1 + pc2; }
                for (int q = 0; q < r; ++q) x &= x - 1;  // drop r lowest set bits
                val = pzs[(lane << 8) + base + (__ffsll(x) - 1)];
            }
            vv[sel] = __shfl(val, src, 64);
        }
        if (lane == 0) {
            float med = 0.5f * (vv[0] + vv[1]);
            out[og] = (med + 48.0f) * (1.0f / 96.0f);
        }
    }
}

extern "C" void kernel_launch(void* const* d_in, const int* in_sizes, int n_in,
                              void* d_out, int out_size, void* d_ws, size_t ws_size,
                              hipStream_t stream) {
    const float* pts = (const float*)d_in[0];
    float* out = (float*)d_out;

    char* ws = (char*)d_ws;
    unsigned* nn2 = (unsigned*)(ws + 0);
    int* rank     = (int*)(ws + 32768);
    float2* pxy   = (float2*)(ws + 65536);
    float* pzs    = (float*)(ws + 131072);
    float* delta2 = (float*)(ws + 163840);

    k_init<<<NPTS / 256, 256, 0, stream>>>(nn2, rank);
    k_nn_rank<<<dim3(32, 32), 256, 0, stream>>>(pts, nn2, rank);
    k_mid<<<NPTS / 256, 256, 0, stream>>>(pts, rank, nn2, pxy, pzs, delta2);
    k_median<<<dim3(12, 96), 256, 0, stream>>>(pxy, pzs, delta2, out);
}

// Round 4
// 107.471 us; speedup vs baseline: 1.7650x; 1.0568x over previous
//
#include <hip/hip_runtime.h>
#include <hip/hip_bf16.h>

#define NPTS 8192
#define NSL 64          // j-slices (128 points each)
#define HF 96.0f

// Workspace layout (bytes):
//   0        : float  nn2p[64][8192]   partial min d2 (unclamped) per (slice, i)
//   2097152  : int    rkp [64][8192]   partial pz-rank per (slice, i)
//   4194304  : float2 pxy[8192]        (px,py) sorted by pz
//   4259840  : float  pzs[8192]
//   4292608  : double sum_part[32]     per-block partial sums of nn_dist
// No init kernel needed: every cell written exactly once, no atomics.

// monotone (z, idx) -> u64 key; strict total order, one v_cmp_lt_u64 per pair
__device__ __forceinline__ unsigned long long zkey(float z, int idx) {
    unsigned u = __float_as_uint(z);
    unsigned m = (unsigned)((int)u >> 31) | 0x80000000u;  // neg: FFFFFFFF, pos: 80000000
    return ((unsigned long long)(u ^ m) << 13) | (unsigned)idx;
}

// grid (32 i-blocks, 64 j-slices of 128), block 256 -> 2048 blocks, 8/CU, 100% occ.
// Writes partial NN-min and partial rank; no atomics, no init.
__global__ __launch_bounds__(256) void k_nn_rank(const float* __restrict__ pts,
                                                 float* __restrict__ nn2p,
                                                 int* __restrict__ rkp) {
    __shared__ float4 s4[128];               // (px, py, pz, sq)
    __shared__ unsigned long long sk[128];   // z-order key
    const int tid = threadIdx.x;
    const int bx = blockIdx.x, by = blockIdx.y;
    const int i = bx * 256 + tid;
    const int j0 = by * 128;
    if (tid < 128) {
        int j = j0 + tid;
        float x = pts[3 * j + 0] * HF;
        float y = pts[3 * j + 1] * HF;
        float z = pts[3 * j + 2] * HF;
        s4[tid] = make_float4(x, y, z, x * x + y * y + z * z);
        sk[tid] = zkey(z, j);
    }
    const float xi = pts[3 * i + 0] * HF;
    const float yi = pts[3 * i + 1] * HF;
    const float zi = pts[3 * i + 2] * HF;
    const float sqi = xi * xi + yi * yi + zi * zi;
    const unsigned long long ki = zkey(zi, i);
    __syncthreads();

    float mn = 3.0e38f;
    int rk = 0;
    // self-pair occurs iff this j-slice covers i; condition is wave-uniform
    // (tid>>7 constant within a wave), so no divergence.
    const bool has_self = (by == 2 * bx + (tid >> 7));
    if (!has_self) {
        #pragma unroll 8
        for (int k = 0; k < 128; ++k) {
            float4 p = s4[k];
            // reference formula: sq_i + sq_j - 2*dot
            float d2 = sqi + p.w - 2.0f * (xi * p.x + yi * p.y + zi * p.z);
            mn = fminf(mn, d2);
            rk += (int)(sk[k] < ki);   // stable pz rank (index tiebreak)
        }
    } else {
        const int self_k = tid & 127;
        #pragma unroll 8
        for (int k = 0; k < 128; ++k) {
            float4 p = s4[k];
            float d2 = sqi + p.w - 2.0f * (xi * p.x + yi * p.y + zi * p.z);
            if (k != self_k) mn = fminf(mn, d2);
            rk += (int)(sk[k] < ki);
        }
    }
    nn2p[by * NPTS + i] = mn;   // coalesced, written exactly once
    rkp [by * NPTS + i] = rk;
}

// grid 32, block 256. Reduce partials -> nn_dist + total rank; scatter into
// pz-sorted order; per-block double partial sum of nn_dist.
__global__ __launch_bounds__(256) void k_mid(const float* __restrict__ pts,
                                             const float* __restrict__ nn2p,
                                             const int* __restrict__ rkp,
                                             float2* __restrict__ pxy,
                                             float* __restrict__ pzs,
                                             double* __restrict__ sum_part) {
    const int t = threadIdx.x;
    const int i = blockIdx.x * 256 + t;
    float mn = 3.0e38f;
    int rk = 0;
    #pragma unroll 8
    for (int s = 0; s < NSL; ++s) {
        mn = fminf(mn, nn2p[s * NPTS + i]);   // coalesced across threads
        rk += rkp[s * NPTS + i];
    }
    // clamp commutes with min across slices: min_s max(m_s,0) == max(min_s,0)
    const float nnd = sqrtf(fmaxf(mn, 0.0f));
    pxy[rk] = make_float2(pts[3 * i + 0] * HF, pts[3 * i + 1] * HF);
    pzs[rk] = pts[3 * i + 2] * HF;

    double acc = (double)nnd;
    #pragma unroll
    for (int off = 32; off > 0; off >>= 1) acc += __shfl_down(acc, off, 64);
    __shared__ double sw[4];
    if ((t & 63) == 0) sw[t >> 6] = acc;
    __syncthreads();
    if (t == 0) sum_part[blockIdx.x] = sw[0] + sw[1] + sw[2] + sw[3];
}

// One block per (row, group of 8 cols). Thread t owns point 256k+t of chunk k
// (pz-sorted order) -> coalesced float2 loads. Membership recorded as per-wave
// 64-bit ballots in LDS; rank selection done per-wave in the epilogue.
// delta2 is finalized per-block from the 32 double partials (deterministic:
// same values, same order -> identical result in every block).
// NOTE: replicates reference exactly: px upper bound uses Yr (row-uniform), not Xr.
__global__ __launch_bounds__(256) void k_median(const float2* __restrict__ pxy,
                                                const float* __restrict__ pzs,
                                                const double* __restrict__ sum_part,
                                                float* __restrict__ out) {
    __shared__ unsigned long long bal[8][4][32];  // [cell][wave][chunk]
    __shared__ float s_dd;
    const int t = threadIdx.x;
    const int lane = t & 63;
    const int w = t >> 6;
    const int row = blockIdx.y;      // 96
    const int cg = blockIdx.x;       // 12 col-groups of 8
    if (t == 0) {
        double s = 0.0;
        #pragma unroll
        for (int b = 0; b < 32; ++b) s += sum_part[b];
        float mean = (float)(s / (double)NPTS);
        float avg = 3.0f * mean;     // M_FACTOR * mean
        s_dd = 3.0f * avg;           // M_FACTOR * avg
    }
    __syncthreads();
    const float d = s_dd;
    const float Yf = (float)(row - 48);
    const float ylo = Yf - d, yhi = Yf + d, xhi = Yf + d;
    float xlo[8];
    #pragma unroll
    for (int c = 0; c < 8; ++c) xlo[c] = (float)(cg * 8 + c - 48) - d;

    #pragma unroll 4
    for (int k = 0; k < 32; ++k) {
        float2 p = pxy[(k << 8) + t];
        bool pre = (p.y >= ylo) && (p.y <= yhi) && (p.x <= xhi);
        unsigned long long b[8];
        #pragma unroll
        for (int c = 0; c < 8; ++c) b[c] = __ballot(pre && (p.x >= xlo[c]));
        if (lane == 0) {
            #pragma unroll
            for (int c = 0; c < 8; ++c) bal[c][w][k] = b[c];
        }
    }
    __syncthreads();

    // wave w handles cells 2w and 2w+1; lanes 0..31 each own one chunk
    #pragma unroll
    for (int c2 = 0; c2 < 2; ++c2) {
        const int c = w * 2 + c2;
        const int l = (lane < 32) ? lane : 31;
        const unsigned long long bw0 = bal[c][0][l];
        const unsigned long long bw1 = bal[c][1][l];
        const unsigned long long bw2 = bal[c][2][l];
        const unsigned long long bw3 = bal[c][3][l];
        const int cnt = __popcll(bw0) + __popcll(bw1) + __popcll(bw2) + __popcll(bw3);
        const int cl = (lane < 32) ? cnt : 0;
        int incl = cl;
        #pragma unroll
        for (int off = 1; off < 64; off <<= 1) {
            int v = __shfl_up(incl, off, 64);
            if (lane >= off) incl += v;
        }
        const int ct = __shfl(incl, 63, 64);  // total count c
        const int og = row * 96 + cg * 8 + c;
        if (ct == 0) {
            if (lane == 0) out[og] = 0.0f;
            continue;
        }
        const int excl = incl - cl;
        float vv[2];
        #pragma unroll
        for (int sel = 0; sel < 2; ++sel) {
            const int target = sel ? (ct >> 1) : ((ct - 1) >> 1);
            const bool pred = (lane < 32) && (target >= excl) && (target < excl + cl);
            unsigned long long bm = __ballot(pred);
            int src = __ffsll(bm) - 1;  // exactly one lane holds the target
            float val = 0.0f;
            if (pred) {
                int r = target - excl;
                int pc0 = __popcll(bw0), pc1 = __popcll(bw1), pc2 = __popcll(bw2);
                unsigned long long x;
                int base;
                if (r < pc0)              { x = bw0; base = 0; }
                else if (r < pc0 + pc1)   { x = bw1; base = 64;  r -= pc0; }
                else if (r < pc0+pc1+pc2) { x = bw2; base = 128; r -= pc0 + pc1; }
                else                      { x = bw3; base = 192; r -= pc0 + pc1 + pc2; }
                for (int q = 0; q < r; ++q) x &= x - 1;  // drop r lowest set bits
                val = pzs[(lane << 8) + base + (__ffsll(x) - 1)];
            }
            vv[sel] = __shfl(val, src, 64);
        }
        if (lane == 0) {
            float med = 0.5f * (vv[0] + vv[1]);
            out[og] = (med + 48.0f) * (1.0f / 96.0f);
        }
    }
}

extern "C" void kernel_launch(void* const* d_in, const int* in_sizes, int n_in,
                              void* d_out, int out_size, void* d_ws, size_t ws_size,
                              hipStream_t stream) {
    const float* pts = (const float*)d_in[0];
    float* out = (float*)d_out;

    char* ws = (char*)d_ws;
    float* nn2p      = (float*)(ws + 0);
    int* rkp         = (int*)(ws + 2097152);
    float2* pxy      = (float2*)(ws + 4194304);
    float* pzs       = (float*)(ws + 4259840);
    double* sum_part = (double*)(ws + 4292608);

    k_nn_rank<<<dim3(32, NSL), 256, 0, stream>>>(pts, nn2p, rkp);
    k_mid<<<32, 256, 0, stream>>>(pts, nn2p, rkp, pxy, pzs, sum_part);
    k_median<<<dim3(12, 96), 256, 0, stream>>>(pxy, pzs, sum_part, out);
}